// Round 4
// baseline (121.746 us; speedup 1.0000x reference)
//
#include <hip/hip_runtime.h>
#include <hip/hip_bf16.h>

#define NB  8
#define ENW 512
#define DEW 64
#define EMB 512
#define UN  512
#define NT  100

// k = 2*log2(e): folded into w_en, w_de, tw so that exp2(att2+bias2) = e^{2x}
#define KSCALE 2.8853900817779268f
#define L2E    1.4426950408889634f

typedef short bf16x8 __attribute__((ext_vector_type(8)));
typedef unsigned short u16x8 __attribute__((ext_vector_type(8)));
typedef float f32x4  __attribute__((ext_vector_type(4)));

__device__ __forceinline__ unsigned short f2bf(float f) {   // RNE
    union { float f; unsigned int u; } v; v.f = f;
    unsigned int r = v.u + 0x7FFFu + ((v.u >> 16) & 1u);
    return (unsigned short)(r >> 16);
}

// ---------------- fused MFMA GEMM (en + de), prep folded in ----------------
// bx<64:  Ea[m][u] = exp2(bf16(en[m])·bf16(K*w_en)[:,u])            (M=4096)
// bx>=64: Eb[m][u] = exp2(bf16(de[m])·bf16(K*w_de)[:,u] + tw2[b][u]) (M=512)
// B-tile built in-block from w f32 columns: transpose + f2bf + XOR-swizzled
// ds_write_b128 (swizzle matches the proven read path: col ^ ((row&7)<<3)).
// A read f32, packed to bf16 in-register (bit-identical to old prep's f2bf).
// tw2 computed by wave 0 of the 8 de-blocks.  Zero barriers in the K-loop.
__global__ __launch_bounds__(256) void gemm_all(const float* __restrict__ en,
                                                const float* __restrict__ de,
                                                const float* __restrict__ w_en,
                                                const float* __restrict__ w_de,
                                                const float* __restrict__ topics,
                                                const float* __restrict__ wt_mat,
                                                float* __restrict__ Ea,
                                                float* __restrict__ Eb) {
    __shared__ unsigned short Blds[64 * 512];   // 64 KB
    __shared__ float tws[64];
    const int N = 512;
    const int bx = blockIdx.x;
    const bool is_de = (bx >= 64);
    const float* A = is_de ? de : en;
    const float* W = is_de ? w_de : w_en;
    float* C = is_de ? Eb : Ea;
    const int mb = is_de ? (bx - 64) : bx;

    const int t = threadIdx.x;
    const int lane = t & 63;
    const int wave = t >> 6;
    const int n0 = blockIdx.y * 64;

    // ---- stage B-tile: thread (u = t&63, q = t>>6) covers e = m*32 + q*8 + [0,8) ----
    {
        const int u = t & 63;
        const int q = t >> 6;
        const int sw = (u & 7) << 3;
        const float* wcol = W + n0 + u;          // column u of W[e][n]
        unsigned short* brow = &Blds[u * 512];
#pragma unroll
        for (int m = 0; m < 16; ++m) {
            const int e0 = m * 32 + q * 8;
            const float* p = wcol + (size_t)e0 * 512;
            bf16x8 o;
#pragma unroll
            for (int j = 0; j < 8; ++j)
                o[j] = (short)f2bf(KSCALE * p[(size_t)j * 512]);
            *(bf16x8*)&brow[e0 ^ sw] = o;
        }
    }
    // ---- tw2 for de-blocks: wave 0, one u per lane ----
    if (is_de && t < 64) {
        const float* tp = topics + mb * NT;
        const float* wp = wt_mat + (size_t)(n0 + t) * NT;
        float s = 0.f;
        for (int tt = 0; tt < NT; ++tt) s += tp[tt] * wp[tt];
        tws[t] = KSCALE * s;
    }

    const int m0 = mb * 64 + wave * 16;
    const int row = m0 + (lane & 15);
    const int kq  = (lane >> 4) * 8;
    const int nrow = lane & 15;
    const int swz = (nrow & 7) << 3;           // same for all nn since 16 ≡ 0 (mod 8)

    f32x4 acc[4];
#pragma unroll
    for (int nn = 0; nn < 4; ++nn) acc[nn] = 0.f;

    const float* apf = A + (size_t)row * 512 + kq;
    // prefetch + pack first A group BEFORE the barrier (independent of staging)
    bf16x8 apre[4];
#pragma unroll
    for (int qq = 0; qq < 4; ++qq) {
        float4 x0 = *(const float4*)(apf + qq * 32);
        float4 x1 = *(const float4*)(apf + qq * 32 + 4);
        bf16x8 o;
        o[0] = (short)f2bf(x0.x); o[1] = (short)f2bf(x0.y);
        o[2] = (short)f2bf(x0.z); o[3] = (short)f2bf(x0.w);
        o[4] = (short)f2bf(x1.x); o[5] = (short)f2bf(x1.y);
        o[6] = (short)f2bf(x1.z); o[7] = (short)f2bf(x1.w);
        apre[qq] = o;
    }

    __syncthreads();                            // staging + tws complete
#pragma unroll
    for (int g = 0; g < 4; ++g) {
        bf16x8 acur[4];
#pragma unroll
        for (int qq = 0; qq < 4; ++qq) acur[qq] = apre[qq];
        if (g < 3) {
#pragma unroll
            for (int qq = 0; qq < 4; ++qq) {
                float4 x0 = *(const float4*)(apf + (g + 1) * 128 + qq * 32);
                float4 x1 = *(const float4*)(apf + (g + 1) * 128 + qq * 32 + 4);
                bf16x8 o;
                o[0] = (short)f2bf(x0.x); o[1] = (short)f2bf(x0.y);
                o[2] = (short)f2bf(x0.z); o[3] = (short)f2bf(x0.w);
                o[4] = (short)f2bf(x1.x); o[5] = (short)f2bf(x1.y);
                o[6] = (short)f2bf(x1.z); o[7] = (short)f2bf(x1.w);
                apre[qq] = o;
            }
        }
#pragma unroll
        for (int qq = 0; qq < 4; ++qq) {
            const int kc = g * 128 + qq * 32;
            const int col = (kq + kc) ^ swz;
#pragma unroll
            for (int nn = 0; nn < 4; ++nn) {
                bf16x8 b = *(const bf16x8*)&Blds[(nrow + nn * 16) * 512 + col];
                acc[nn] = __builtin_amdgcn_mfma_f32_16x16x32_bf16(acur[qq], b, acc[nn], 0, 0, 0);
            }
        }
    }
    const int crow = m0 + (lane >> 4) * 4;
    const int ccol = lane & 15;
#pragma unroll
    for (int nn = 0; nn < 4; ++nn)
#pragma unroll
        for (int r = 0; r < 4; ++r) {
            int rw = crow + r, cl = n0 + nn * 16 + ccol;
            float v = acc[nn][r];
            if (is_de) v += tws[nn * 16 + ccol];
            C[(size_t)rw * N + cl] = __builtin_amdgcn_exp2f(v);
        }
}

// ---------------- mu partials: register-tiled 1j x 4i, 4-way rcp combining ----------
// sum_{u in 4} n_u/q_u = (nA*dB + nB*dA)/(dA*dB); nu loaded raw, -2 folded into the
// final store (num is linear in nu -> algebraically exact).
__global__ __launch_bounds__(256) void mu5_kernel(const float* __restrict__ Ea,
                                                  const float* __restrict__ Eb,
                                                  const float* __restrict__ nu,
                                                  float* __restrict__ mu0,
                                                  float* __restrict__ mu1) {
    __shared__ float As[64][132];
    __shared__ float Bs[16][132];
    const int t = threadIdx.x;
    const int bx = blockIdx.x;
    const int us = bx & 1;
    const int it = (bx >> 1) & 7;
    const int jt = (bx >> 4) & 3;
    const int b  = bx >> 6;
    const int i0 = it * 64, j0 = jt * 16, u0 = us * 256;
    const int il = t & 15, jr = t >> 4;

    const float* aeb = Ea + (size_t)(b * ENW + i0) * UN;
    const float* beb = Eb + (size_t)(b * DEW + j0) * UN;

    float s0 = 0.f, s1 = 0.f, s2 = 0.f, s3 = 0.f;
#pragma unroll
    for (int half = 0; half < 2; ++half) {
        const int uc = u0 + half * 128;
#pragma unroll
        for (int q = 0; q < 8; ++q) {
            int idx = q * 256 + t;
            int rowi = idx >> 5, c4 = idx & 31;
            *(float4*)&As[rowi][c4 * 4] = *(const float4*)(aeb + (size_t)rowi * UN + uc + c4 * 4);
        }
#pragma unroll
        for (int q = 0; q < 2; ++q) {
            int idx = q * 256 + t;
            int rowi = idx >> 5, c4 = idx & 31;
            *(float4*)&Bs[rowi][c4 * 4] = *(const float4*)(beb + (size_t)rowi * UN + uc + c4 * 4);
        }
        __syncthreads();
#pragma unroll 8
        for (int c = 0; c < 32; ++c) {
            float4 bb = *(const float4*)&Bs[jr][c * 4];
            float4 nv = *(const float4*)(nu + uc + c * 4);   // uniform -> s_load
            float4 a0 = *(const float4*)&As[il][c * 4];
            float4 a1 = *(const float4*)&As[il + 16][c * 4];
            float4 a2 = *(const float4*)&As[il + 32][c * 4];
            float4 a3 = *(const float4*)&As[il + 48][c * 4];
            {
                float q0 = fmaf(a0.x, bb.x, 1.f), q1 = fmaf(a0.y, bb.y, 1.f);
                float q2 = fmaf(a0.z, bb.z, 1.f), q3 = fmaf(a0.w, bb.w, 1.f);
                float dA = q0 * q1, dB = q2 * q3;
                float nA = fmaf(nv.y, q0, nv.x * q1);
                float nB = fmaf(nv.w, q2, nv.z * q3);
                float num = fmaf(nB, dA, nA * dB);
                s0 = fmaf(num, __builtin_amdgcn_rcpf(dA * dB), s0);
            }
            {
                float q0 = fmaf(a1.x, bb.x, 1.f), q1 = fmaf(a1.y, bb.y, 1.f);
                float q2 = fmaf(a1.z, bb.z, 1.f), q3 = fmaf(a1.w, bb.w, 1.f);
                float dA = q0 * q1, dB = q2 * q3;
                float nA = fmaf(nv.y, q0, nv.x * q1);
                float nB = fmaf(nv.w, q2, nv.z * q3);
                float num = fmaf(nB, dA, nA * dB);
                s1 = fmaf(num, __builtin_amdgcn_rcpf(dA * dB), s1);
            }
            {
                float q0 = fmaf(a2.x, bb.x, 1.f), q1 = fmaf(a2.y, bb.y, 1.f);
                float q2 = fmaf(a2.z, bb.z, 1.f), q3 = fmaf(a2.w, bb.w, 1.f);
                float dA = q0 * q1, dB = q2 * q3;
                float nA = fmaf(nv.y, q0, nv.x * q1);
                float nB = fmaf(nv.w, q2, nv.z * q3);
                float num = fmaf(nB, dA, nA * dB);
                s2 = fmaf(num, __builtin_amdgcn_rcpf(dA * dB), s2);
            }
            {
                float q0 = fmaf(a3.x, bb.x, 1.f), q1 = fmaf(a3.y, bb.y, 1.f);
                float q2 = fmaf(a3.z, bb.z, 1.f), q3 = fmaf(a3.w, bb.w, 1.f);
                float dA = q0 * q1, dB = q2 * q3;
                float nA = fmaf(nv.y, q0, nv.x * q1);
                float nB = fmaf(nv.w, q2, nv.z * q3);
                float num = fmaf(nB, dA, nA * dB);
                s3 = fmaf(num, __builtin_amdgcn_rcpf(dA * dB), s3);
            }
        }
        __syncthreads();
    }
    float* mo = us ? mu1 : mu0;
    const size_t base = (size_t)(b * DEW + j0 + jr) * ENW + i0 + il;
    mo[base]      = -2.f * s0;
    mo[base + 16] = -2.f * s1;
    mo[base + 32] = -2.f * s2;
    mo[base + 48] = -2.f * s3;
}

// ---------------- fused softmax + p_gen + alphas + out (512 threads) ----------------
// grid 256: eh=bx&1, jq=(bx>>1)&15, b=bx>>5.  8 waves: phase1 waves 0-3 (softmax,
// one j each); phase2 wave = i-octant (2 waves/SIMD -> latency hiding doubled);
// phase3 waves 0-3 reduce 8 partials.  snu computed per-wave via shfl reduce.
__global__ __launch_bounds__(512) void softfin_kernel(const float* __restrict__ mu0,
                                                      const float* __restrict__ mu1,
                                                      const float* __restrict__ nu,
                                                      const float* __restrict__ en,
                                                      const float* __restrict__ de,
                                                      float* __restrict__ out,
                                                      float* __restrict__ alphas,
                                                      float* __restrict__ p_gen) {
    __shared__ float Al[4][512];
    __shared__ float Ps[8][4][256];
    const int bx = blockIdx.x;
    const int eh = bx & 1;
    const int jq = (bx >> 1) & 15;
    const int b  = bx >> 5;
    const int t = threadIdx.x;
    const int wave = t >> 6, lane = t & 63;
    const int j0 = jq * 4;

    // snu = sum_u nu[u] — per-wave shuffle reduce (no barrier)
    float sn = 0.f;
#pragma unroll
    for (int k = 0; k < 8; ++k) sn += nu[lane + 64 * k];
#pragma unroll
    for (int off = 32; off > 0; off >>= 1) sn += __shfl_xor(sn, off);

    // ---- phase 1: softmax for j = j0 + wave (waves 0-3) ----
    if (wave < 4) {
        const int bj = b * DEW + j0 + wave;
        const float* mup0 = mu0 + (size_t)bj * ENW;
        const float* mup1 = mu1 + (size_t)bj * ENW;
        float v[8], a[8];
#pragma unroll
        for (int c = 0; c < 8; ++c) v[c] = mup0[c * 64 + lane] + mup1[c * 64 + lane] + sn;
        float mx = v[0];
#pragma unroll
        for (int c = 1; c < 8; ++c) mx = fmaxf(mx, v[c]);
#pragma unroll
        for (int off = 32; off > 0; off >>= 1) mx = fmaxf(mx, __shfl_xor(mx, off));
        float s = 0.f;
#pragma unroll
        for (int c = 0; c < 8; ++c) { a[c] = __builtin_amdgcn_exp2f((v[c] - mx) * L2E); s += a[c]; }
#pragma unroll
        for (int off = 32; off > 0; off >>= 1) s += __shfl_xor(s, off);
        float inv = __builtin_amdgcn_rcpf(s);
#pragma unroll
        for (int c = 0; c < 8; ++c) {
            a[c] *= inv;
            Al[wave][c * 64 + lane] = a[c];
        }
        if (eh == 0) {
            float* alp = alphas + (size_t)bj * ENW;
            float* pgp = p_gen + (size_t)bj * ENW;
#pragma unroll
            for (int c = 0; c < 8; ++c) {
                alp[c * 64 + lane] = a[c];
                pgp[c * 64 + lane] = __builtin_amdgcn_rcpf(1.f + __builtin_amdgcn_exp2f(-v[c] * L2E));
            }
        }
    }
    __syncthreads();

    // ---- phase 2: partial sums over i-octant `wave` ----
    const int i0 = wave * 64;
    const float* enb = en + (size_t)b * ENW * EMB + eh * 256 + lane * 4;
    f32x4 acc[4];
#pragma unroll
    for (int jj = 0; jj < 4; ++jj) acc[jj] = 0.f;
#pragma unroll 2
    for (int ig = 0; ig < 64; ig += 4) {
        const int ib = i0 + ig;
        float4 al0 = *(const float4*)&Al[0][ib];
        float4 al1 = *(const float4*)&Al[1][ib];
        float4 al2 = *(const float4*)&Al[2][ib];
        float4 al3 = *(const float4*)&Al[3][ib];
#pragma unroll
        for (int r = 0; r < 4; ++r) {
            float4 x = *(const float4*)(enb + (size_t)(ib + r) * EMB);
            float w0 = (r == 0) ? al0.x : (r == 1) ? al0.y : (r == 2) ? al0.z : al0.w;
            float w1 = (r == 0) ? al1.x : (r == 1) ? al1.y : (r == 2) ? al1.z : al1.w;
            float w2 = (r == 0) ? al2.x : (r == 1) ? al2.y : (r == 2) ? al2.z : al2.w;
            float w3 = (r == 0) ? al3.x : (r == 1) ? al3.y : (r == 2) ? al3.z : al3.w;
            acc[0][0] = fmaf(w0, x.x, acc[0][0]); acc[0][1] = fmaf(w0, x.y, acc[0][1]);
            acc[0][2] = fmaf(w0, x.z, acc[0][2]); acc[0][3] = fmaf(w0, x.w, acc[0][3]);
            acc[1][0] = fmaf(w1, x.x, acc[1][0]); acc[1][1] = fmaf(w1, x.y, acc[1][1]);
            acc[1][2] = fmaf(w1, x.z, acc[1][2]); acc[1][3] = fmaf(w1, x.w, acc[1][3]);
            acc[2][0] = fmaf(w2, x.x, acc[2][0]); acc[2][1] = fmaf(w2, x.y, acc[2][1]);
            acc[2][2] = fmaf(w2, x.z, acc[2][2]); acc[2][3] = fmaf(w2, x.w, acc[2][3]);
            acc[3][0] = fmaf(w3, x.x, acc[3][0]); acc[3][1] = fmaf(w3, x.y, acc[3][1]);
            acc[3][2] = fmaf(w3, x.z, acc[3][2]); acc[3][3] = fmaf(w3, x.w, acc[3][3]);
        }
    }
#pragma unroll
    for (int jj = 0; jj < 4; ++jj)
        *(f32x4*)&Ps[wave][jj][lane * 4] = acc[jj];
    __syncthreads();

    // ---- phase 3: reduce over 8 i-octants; waves 0-3, one j each ----
    if (wave < 4) {
        const int bj = b * DEW + j0 + wave;
        const int e = eh * 256 + lane * 4;
        float4 p0 = *(const float4*)&Ps[0][wave][lane * 4];
        float4 p1 = *(const float4*)&Ps[1][wave][lane * 4];
        float4 p2 = *(const float4*)&Ps[2][wave][lane * 4];
        float4 p3 = *(const float4*)&Ps[3][wave][lane * 4];
        float4 p4 = *(const float4*)&Ps[4][wave][lane * 4];
        float4 p5 = *(const float4*)&Ps[5][wave][lane * 4];
        float4 p6 = *(const float4*)&Ps[6][wave][lane * 4];
        float4 p7 = *(const float4*)&Ps[7][wave][lane * 4];
        float4 d = *(const float4*)(de + (size_t)bj * EMB + e);
        float4 o;
        o.x = d.x + ((p0.x + p1.x) + (p2.x + p3.x)) + ((p4.x + p5.x) + (p6.x + p7.x));
        o.y = d.y + ((p0.y + p1.y) + (p2.y + p3.y)) + ((p4.y + p5.y) + (p6.y + p7.y));
        o.z = d.z + ((p0.z + p1.z) + (p2.z + p3.z)) + ((p4.z + p5.z) + (p6.z + p7.z));
        o.w = d.w + ((p0.w + p1.w) + (p2.w + p3.w)) + ((p4.w + p5.w) + (p6.w + p7.w));
        *(float4*)(out + (size_t)bj * EMB + e) = o;
    }
}

extern "C" void kernel_launch(void* const* d_in, const int* in_sizes, int n_in,
                              void* d_out, int out_size, void* d_ws, size_t ws_size,
                              hipStream_t stream) {
    const float* en     = (const float*)d_in[0];  // [8][512][512]
    const float* de     = (const float*)d_in[1];  // [8][64][512]
    const float* topics = (const float*)d_in[2];  // [8][100]
    const float* w_en   = (const float*)d_in[3];  // [512][512]
    const float* w_de   = (const float*)d_in[4];  // [512][512]
    const float* nu     = (const float*)d_in[5];  // [512]
    const float* wt     = (const float*)d_in[6];  // [512][100]

    float* out    = (float*)d_out;        // [8][64][512]
    float* alphas = out + 262144;
    float* p_gen  = out + 524288;

    // Workspace: 11,534,336 B total (well under proven bound).
    char* ws = (char*)d_ws;
    float* Ea  = (float*)(ws);              //  8388608 B
    float* Eb  = (float*)(ws + 8388608);    //  1048576 B
    float* mu0 = (float*)(ws + 9437184);    //  1048576 B
    float* mu1 = (float*)(ws + 10485760);   //  1048576 B

    gemm_all<<<dim3(72, 8), 256, 0, stream>>>(en, de, w_en, w_de, topics, wt, Ea, Eb);
    mu5_kernel<<<512, 256, 0, stream>>>(Ea, Eb, nu, mu0, mu1);
    softfin_kernel<<<256, 512, 0, stream>>>(mu0, mu1, nu, en, de, out, alphas, p_gen);
}